// Round 3
// baseline (1245.995 us; speedup 1.0000x reference)
//
#include <hip/hip_runtime.h>
#include <cstdint>

#define Bn 16
#define Nn 4096
#define Cn 64
#define NPOINT 1024
#define NSAMPLE 32

// ---------------------------------------------------------------------------
// u64 argmax key: (dist_bits << 32) | ~index.
// dist >= 0 so its IEEE bits are monotone as u32; max key = max dist,
// ties -> max ~index = MIN index (matches jnp.argmax first-occurrence).
// ---------------------------------------------------------------------------
__device__ __forceinline__ unsigned long long fps_wave_max(unsigned long long k) {
  // Canonical GCN/CDNA wave64 prefix reduction via DPP; lane 63 ends with max.
  // bound_ctrl=false + old=self => invalid-source lanes are a no-op for max.
#define FPS_STEP(CTRL)                                                          \
  {                                                                             \
    unsigned int lo = (unsigned int)k, hi = (unsigned int)(k >> 32);            \
    unsigned int tlo =                                                          \
        (unsigned int)__builtin_amdgcn_update_dpp((int)lo, (int)lo, CTRL, 0xF, 0xF, false); \
    unsigned int thi =                                                          \
        (unsigned int)__builtin_amdgcn_update_dpp((int)hi, (int)hi, CTRL, 0xF, 0xF, false); \
    unsigned long long t = ((unsigned long long)thi << 32) | tlo;               \
    if (t > k) k = t;                                                           \
  }
  FPS_STEP(0x111)  // row_shr:1
  FPS_STEP(0x112)  // row_shr:2
  FPS_STEP(0x114)  // row_shr:4
  FPS_STEP(0x118)  // row_shr:8  -> lane15 of each row16 has row max
  FPS_STEP(0x142)  // row_bcast:15 -> lane31 has max of lanes 0..31
  FPS_STEP(0x143)  // row_bcast:31 -> lane63 has max of lanes 0..63
#undef FPS_STEP
  return k;
}

// ---------------------------------------------------------------------------
// Kernel 1: farthest point sampling. One block (256 threads) per batch.
// Points + running min-dists in registers (16/thread); float4 point mirror in
// LDS for centroid broadcast (1 ds_read_b128). Per-thread argmax tracked as
// (f32,best_idx); u64 key packed once per iteration for the cross-lane max.
// One barrier per iteration (double-buffered partials). Records the
// PRE-update farthest each iteration (matches the lax.scan carry).
// ---------------------------------------------------------------------------
__global__ __launch_bounds__(256) void fps_kernel(const float* __restrict__ xyz,
                                                  float* __restrict__ new_xyz) {
  const int b = blockIdx.x;
  const int t = threadIdx.x;
  const float* px = xyz + b * Nn * 3;

  __shared__ __align__(16) float4 sp[Nn];               // 64 KiB (16 blocks total; fine)
  __shared__ __align__(16) unsigned long long rk[2][4];

  float X[16], Y[16], Z[16], D[16];
#pragma unroll
  for (int j = 0; j < 16; ++j) {
    int i = j * 256 + t;
    float x = px[i * 3 + 0];
    float y = px[i * 3 + 1];
    float z = px[i * 3 + 2];
    sp[i] = make_float4(x, y, z, 0.0f);
    X[j] = x; Y[j] = y; Z[j] = z;
    D[j] = 1e10f;
  }
  __syncthreads();

  int far = 0;
  float* out = new_xyz + b * NPOINT * 3;

  for (int it = 0; it < NPOINT; ++it) {
    float4 c = sp[far];  // uniform address -> LDS broadcast
    if (t == 0) {
      out[it * 3 + 0] = c.x;
      out[it * 3 + 1] = c.y;
      out[it * 3 + 2] = c.z;
    }

    float bd = -1.0f;
    int   bi = 0;
#pragma unroll
    for (int j = 0; j < 16; ++j) {
#pragma clang fp contract(off)
      // mul+add (no fma), left-assoc: matches XLA's elementwise lowering
      float dx = X[j] - c.x, dy = Y[j] - c.y, dz = Z[j] - c.z;
      float d = (dx * dx + dy * dy) + dz * dz;
      float nd = fminf(D[j], d);
      D[j] = nd;
      // strict >, ascending j => equal dists keep the lowest index
      if (nd > bd) { bd = nd; bi = j * 256 + t; }
    }

    unsigned long long k =
        ((unsigned long long)__float_as_uint(bd) << 32) |
        (unsigned int)(~(unsigned int)bi);
    k = fps_wave_max(k);  // lane 63 of each wave holds the wave max

    const int buf = it & 1;
    if ((t & 63) == 63) rk[buf][t >> 6] = k;
    __syncthreads();

    unsigned long long f0 = rk[buf][0];
    unsigned long long f1 = rk[buf][1];
    unsigned long long f2 = rk[buf][2];
    unsigned long long f3 = rk[buf][3];
    if (f1 > f0) f0 = f1;
    if (f2 > f0) f0 = f2;
    if (f3 > f0) f0 = f3;
    far = (int)(~(unsigned int)f0);  // recover index from ~idx in low bits
  }
}

// ---------------------------------------------------------------------------
// Kernel 2: ball query. One wave per centroid; ballot+popcount compaction of
// the first NSAMPLE in-radius indices in ascending order, pad with the first
// hit (the centroid itself always passes -> first is always valid).
// Distance uses the reference's expanded form ||c||^2 - 2 c.p + ||p||^2.
// ---------------------------------------------------------------------------
__global__ __launch_bounds__(256) void ballquery_kernel(const float* __restrict__ xyz,
                                                        const float* __restrict__ new_xyz,
                                                        int* __restrict__ bidx) {
  const int gw = (int)((blockIdx.x * 256 + threadIdx.x) >> 6);
  const int lane = threadIdx.x & 63;
  if (gw >= Bn * NPOINT) return;
  const int b = gw >> 10;
  const float* px = xyz + b * Nn * 3;
  const float R2 = 0.04f;  // float(0.2*0.2 in double) == 0.04f

  float cx = new_xyz[gw * 3 + 0];
  float cy = new_xyz[gw * 3 + 1];
  float cz = new_xyz[gw * 3 + 2];
  float cs;
  {
#pragma clang fp contract(off)
    cs = (cx * cx + cy * cy) + cz * cz;
  }

  int* out = bidx + gw * NSAMPLE;
  int found = 0;
  int first = -1;

  for (int base = 0; base < Nn && found < NSAMPLE; base += 64) {
    int i = base + lane;
    float x = px[i * 3 + 0];
    float y = px[i * 3 + 1];
    float z = px[i * 3 + 2];
    float ps, sqr;
    // dot like a GEMM k-loop: fma accumulation, k ascending
    float dot = fmaf(cx, x, 0.0f);
    dot = fmaf(cy, y, dot);
    dot = fmaf(cz, z, dot);
    {
#pragma clang fp contract(off)
      ps = (x * x + y * y) + z * z;
      sqr = (cs - 2.0f * dot) + ps;
    }
    bool pass = !(sqr > R2);
    unsigned long long m = __ballot(pass);
    if (first < 0 && m) first = base + (__ffsll(m) - 1);
    int rank = (int)__popcll(m & ((1ULL << lane) - 1ULL));
    int pos = found + rank;
    if (pass && pos < NSAMPLE) out[pos] = i;
    found += (int)__popcll(m);
  }

  int cnt = found < NSAMPLE ? found : NSAMPLE;
  for (int k = cnt + lane; k < NSAMPLE; k += 64) out[k] = first;
}

// ---------------------------------------------------------------------------
// Kernel 3: gather + concat + 3x (linear+ReLU) + max over samples, fused.
// One wave (64 threads) per centroid. X (32x67) and H (32x64) staged in LDS
// (same-wave LDS ops are in-order -> no barriers needed). Each thread owns
// output column d=lane; weight columns from global (L1/L2-resident, all
// blocks read the same ~65KB). Layer 2 computes both output halves
// (dd=lane, dd=lane+64) in ONE pass so the Xw broadcast reads are shared.
// ---------------------------------------------------------------------------
__global__ __launch_bounds__(64) void group_mlp_kernel(
    const float* __restrict__ xyz, const float* __restrict__ points,
    const float* __restrict__ w0, const float* __restrict__ b0,
    const float* __restrict__ w1, const float* __restrict__ b1,
    const float* __restrict__ w2, const float* __restrict__ b2,
    const float* __restrict__ new_xyz, const int* __restrict__ bidx,
    float* __restrict__ out_pts) {
  const int lane = threadIdx.x & 63;
  const int g = blockIdx.x;  // centroid id in [0, B*NPOINT)
  const int b = g >> 10;

  __shared__ __align__(16) float Xw[NSAMPLE][68];  // 67 used; stride 68 keeps rows 16B-aligned
  __shared__ __align__(16) float Hw[NSAMPLE][64];

  const int* bi = bidx + g * NSAMPLE;
  const float c0 = new_xyz[g * 3 + 0];
  const float c1 = new_xyz[g * 3 + 1];
  const float c2 = new_xyz[g * 3 + 2];

  // ---- gather/concat: X[k][0:3] = xyz[idx]-cen, X[k][3:67] = points[idx][0:64]
  for (int k = 0; k < NSAMPLE; ++k) {
    int id = bi[k];
    float v;
    if (lane < 3) {
      v = xyz[(b * Nn + id) * 3 + lane] - (lane == 0 ? c0 : (lane == 1 ? c1 : c2));
    } else {
      v = points[(b * Nn + id) * Cn + (lane - 3)];
    }
    Xw[k][lane] = v;
    if (lane < 3) Xw[k][64 + lane] = points[(b * Nn + id) * Cn + 61 + lane];
  }

  float acc[NSAMPLE];

  // ---- layer 0: 67 -> 64, ReLU  (out column d = lane)
  {
    float bb = b0[lane];
#pragma unroll
    for (int k = 0; k < NSAMPLE; ++k) acc[k] = bb;
    for (int c4 = 0; c4 < 16; ++c4) {
      float wa = w0[(c4 * 4 + 0) * 64 + lane];
      float wb = w0[(c4 * 4 + 1) * 64 + lane];
      float wc = w0[(c4 * 4 + 2) * 64 + lane];
      float wd = w0[(c4 * 4 + 3) * 64 + lane];
#pragma unroll
      for (int k = 0; k < NSAMPLE; ++k) {
        float4 xv = *(const float4*)&Xw[k][c4 * 4];  // uniform addr -> broadcast
        acc[k] += xv.x * wa + xv.y * wb + xv.z * wc + xv.w * wd;
      }
    }
    float wt0 = w0[64 * 64 + lane];
    float wt1 = w0[65 * 64 + lane];
    float wt2 = w0[66 * 64 + lane];
#pragma unroll
    for (int k = 0; k < NSAMPLE; ++k)
      acc[k] += Xw[k][64] * wt0 + Xw[k][65] * wt1 + Xw[k][66] * wt2;
#pragma unroll
    for (int k = 0; k < NSAMPLE; ++k) Hw[k][lane] = fmaxf(acc[k], 0.0f);
  }

  // ---- layer 1: 64 -> 64, ReLU (reads Hw, writes back into Xw)
  {
    float bb = b1[lane];
#pragma unroll
    for (int k = 0; k < NSAMPLE; ++k) acc[k] = bb;
    for (int c4 = 0; c4 < 16; ++c4) {
      float wa = w1[(c4 * 4 + 0) * 64 + lane];
      float wb = w1[(c4 * 4 + 1) * 64 + lane];
      float wc = w1[(c4 * 4 + 2) * 64 + lane];
      float wd = w1[(c4 * 4 + 3) * 64 + lane];
#pragma unroll
      for (int k = 0; k < NSAMPLE; ++k) {
        float4 hv = *(const float4*)&Hw[k][c4 * 4];
        acc[k] += hv.x * wa + hv.y * wb + hv.z * wc + hv.w * wd;
      }
    }
#pragma unroll
    for (int k = 0; k < NSAMPLE; ++k) Xw[k][lane] = fmaxf(acc[k], 0.0f);
  }

  // ---- layer 2: 64 -> 128, ReLU + max over k; BOTH halves in one pass so
  // each Xw broadcast read feeds 8 FMAs instead of 4.
  {
    float accB[NSAMPLE];
    float bbA = b2[lane];
    float bbB = b2[lane + 64];
#pragma unroll
    for (int k = 0; k < NSAMPLE; ++k) { acc[k] = bbA; accB[k] = bbB; }
    for (int c4 = 0; c4 < 16; ++c4) {
      float wa = w2[(c4 * 4 + 0) * 128 + lane];
      float wb = w2[(c4 * 4 + 1) * 128 + lane];
      float wc = w2[(c4 * 4 + 2) * 128 + lane];
      float wd = w2[(c4 * 4 + 3) * 128 + lane];
      float we = w2[(c4 * 4 + 0) * 128 + lane + 64];
      float wf = w2[(c4 * 4 + 1) * 128 + lane + 64];
      float wg = w2[(c4 * 4 + 2) * 128 + lane + 64];
      float wh = w2[(c4 * 4 + 3) * 128 + lane + 64];
#pragma unroll
      for (int k = 0; k < NSAMPLE; ++k) {
        float4 xv = *(const float4*)&Xw[k][c4 * 4];
        acc[k]  += xv.x * wa + xv.y * wb + xv.z * wc + xv.w * wd;
        accB[k] += xv.x * we + xv.y * wf + xv.z * wg + xv.w * wh;
      }
    }
    // max_k relu(acc_k) == max(0, max_k acc_k)
    float mA = 0.0f, mB = 0.0f;
#pragma unroll
    for (int k = 0; k < NSAMPLE; ++k) {
      mA = fmaxf(mA, acc[k]);
      mB = fmaxf(mB, accB[k]);
    }
    float* outp = out_pts + g * 128;
    outp[lane] = mA;
    outp[lane + 64] = mB;
  }
}

// ---------------------------------------------------------------------------
extern "C" void kernel_launch(void* const* d_in, const int* in_sizes, int n_in,
                              void* d_out, int out_size, void* d_ws, size_t ws_size,
                              hipStream_t stream) {
  const float* xyz    = (const float*)d_in[0];
  const float* points = (const float*)d_in[1];
  const float* w0     = (const float*)d_in[2];
  const float* b0     = (const float*)d_in[3];
  const float* w1     = (const float*)d_in[4];
  const float* b1     = (const float*)d_in[5];
  const float* w2     = (const float*)d_in[6];
  const float* b2     = (const float*)d_in[7];

  float* new_xyz = (float*)d_out;                    // (B, NPOINT, 3)
  float* new_pts = (float*)d_out + Bn * NPOINT * 3;  // (B, NPOINT, 128)
  int*   bidx    = (int*)d_ws;                       // (B*NPOINT, NSAMPLE)

  fps_kernel<<<Bn, 256, 0, stream>>>(xyz, new_xyz);
  ballquery_kernel<<<(Bn * NPOINT) / 4, 256, 0, stream>>>(xyz, new_xyz, bidx);
  group_mlp_kernel<<<Bn * NPOINT, 64, 0, stream>>>(xyz, points, w0, b0, w1, b1,
                                                   w2, b2, new_xyz, bidx, new_pts);
}

// Round 4
// 1197.806 us; speedup vs baseline: 1.0402x; 1.0402x over previous
//
#include <hip/hip_runtime.h>
#include <cstdint>

#define Bn 16
#define Nn 4096
#define Cn 64
#define NPOINT 1024
#define NSAMPLE 32

typedef float f32x2 __attribute__((ext_vector_type(2)));

// ---------------------------------------------------------------------------
// u64 argmax key: (dist_bits << 32) | ~index.
// dist >= 0 so its IEEE bits are monotone as u32; max key = max dist,
// ties -> max ~index = MIN index (matches jnp.argmax first-occurrence).
// ---------------------------------------------------------------------------
__device__ __forceinline__ unsigned long long fps_wave_max(unsigned long long k) {
  // Canonical GCN/CDNA wave64 prefix reduction via DPP; lane 63 ends with max.
#define FPS_STEP(CTRL)                                                          \
  {                                                                             \
    unsigned int lo = (unsigned int)k, hi = (unsigned int)(k >> 32);            \
    unsigned int tlo =                                                          \
        (unsigned int)__builtin_amdgcn_update_dpp((int)lo, (int)lo, CTRL, 0xF, 0xF, false); \
    unsigned int thi =                                                          \
        (unsigned int)__builtin_amdgcn_update_dpp((int)hi, (int)hi, CTRL, 0xF, 0xF, false); \
    unsigned long long t = ((unsigned long long)thi << 32) | tlo;               \
    if (t > k) k = t;                                                           \
  }
  FPS_STEP(0x111)  // row_shr:1
  FPS_STEP(0x112)  // row_shr:2
  FPS_STEP(0x114)  // row_shr:4
  FPS_STEP(0x118)  // row_shr:8  -> lane15 of each row16 has row max
  FPS_STEP(0x142)  // row_bcast:15 -> lane31 has max of lanes 0..31
  FPS_STEP(0x143)  // row_bcast:31 -> lane63 has max of lanes 0..63
#undef FPS_STEP
  return k;
}

// ---------------------------------------------------------------------------
// Kernel 1: farthest point sampling. One block (256 threads) per batch.
// Points in packed f32x2 registers (8 pairs/thread) so the distance update
// can use v_pk_{add,mul}_f32; float4 point mirror in LDS for the centroid
// broadcast. Centroid log goes to LDS (sc) and is dumped to global ONCE at
// the end -> no global-store vmcnt(0) drain inside the per-iteration barrier.
// One barrier per iteration (double-buffered partials). Records the
// PRE-update farthest each iteration (matches the lax.scan carry).
// ---------------------------------------------------------------------------
__global__ __launch_bounds__(256) void fps_kernel(const float* __restrict__ xyz,
                                                  float* __restrict__ new_xyz) {
  const int b = blockIdx.x;
  const int t = threadIdx.x;
  const float* px = xyz + b * Nn * 3;

  __shared__ __align__(16) float4 sp[Nn];               // 64 KiB point mirror
  __shared__ __align__(16) float sc[NPOINT * 3];        // 12 KiB centroid log
  __shared__ __align__(16) unsigned long long rk[2][4];

  f32x2 X2[8], Y2[8], Z2[8], D2[8];
#pragma unroll
  for (int p = 0; p < 8; ++p) {
    int i0 = (2 * p) * 256 + t;
    int i1 = (2 * p + 1) * 256 + t;
    float x0 = px[i0 * 3 + 0], y0 = px[i0 * 3 + 1], z0 = px[i0 * 3 + 2];
    float x1 = px[i1 * 3 + 0], y1 = px[i1 * 3 + 1], z1 = px[i1 * 3 + 2];
    sp[i0] = make_float4(x0, y0, z0, 0.0f);
    sp[i1] = make_float4(x1, y1, z1, 0.0f);
    X2[p] = (f32x2){x0, x1};
    Y2[p] = (f32x2){y0, y1};
    Z2[p] = (f32x2){z0, z1};
    D2[p] = (f32x2){1e10f, 1e10f};
  }
  __syncthreads();

  int far = 0;

  for (int it = 0; it < NPOINT; ++it) {
    float4 c = sp[far];  // uniform address -> LDS broadcast
    if (t == 0) {        // LDS-only log; no global store inside the loop
      sc[it * 3 + 0] = c.x;
      sc[it * 3 + 1] = c.y;
      sc[it * 3 + 2] = c.z;
    }

    f32x2 cx2 = {c.x, c.x};
    f32x2 cy2 = {c.y, c.y};
    f32x2 cz2 = {c.z, c.z};

    float bd = -1.0f;
    int   bi = 0;
#pragma unroll
    for (int p = 0; p < 8; ++p) {
#pragma clang fp contract(off)
      // mul+add (no fma), left-assoc: matches XLA's elementwise lowering.
      // Packed pairwise ops are element-independent -> numerics identical
      // to the scalar version.
      f32x2 dx = X2[p] - cx2;
      f32x2 dy = Y2[p] - cy2;
      f32x2 dz = Z2[p] - cz2;
      f32x2 d2 = (dx * dx + dy * dy) + dz * dz;
      f32x2 nd = __builtin_elementwise_min(D2[p], d2);
      D2[p] = nd;
      // ascending global index order (2p, 2p+1); strict > keeps lowest index
      float n0 = nd[0];
      if (n0 > bd) { bd = n0; bi = (2 * p) * 256 + t; }
      float n1 = nd[1];
      if (n1 > bd) { bd = n1; bi = (2 * p + 1) * 256 + t; }
    }

    unsigned long long k =
        ((unsigned long long)__float_as_uint(bd) << 32) |
        (unsigned int)(~(unsigned int)bi);
    k = fps_wave_max(k);  // lane 63 of each wave holds the wave max

    const int buf = it & 1;
    if ((t & 63) == 63) rk[buf][t >> 6] = k;
    __syncthreads();

    unsigned long long f0 = rk[buf][0];
    unsigned long long f1 = rk[buf][1];
    unsigned long long f2 = rk[buf][2];
    unsigned long long f3 = rk[buf][3];
    if (f1 > f0) f0 = f1;
    if (f2 > f0) f0 = f2;
    if (f3 > f0) f0 = f3;
    far = (int)(~(unsigned int)f0);  // recover index from ~idx in low bits
  }

  // one-time dump of the centroid log (coalesced-ish, trivial cost)
  float* out = new_xyz + b * NPOINT * 3;
  for (int i = t; i < NPOINT * 3; i += 256) out[i] = sc[i];
}

// ---------------------------------------------------------------------------
// Kernel 2: ball query. One wave per centroid; ballot+popcount compaction of
// the first NSAMPLE in-radius indices in ascending order, pad with the first
// hit (the centroid itself always passes -> first is always valid).
// Distance uses the reference's expanded form ||c||^2 - 2 c.p + ||p||^2.
// ---------------------------------------------------------------------------
__global__ __launch_bounds__(256) void ballquery_kernel(const float* __restrict__ xyz,
                                                        const float* __restrict__ new_xyz,
                                                        int* __restrict__ bidx) {
  const int gw = (int)((blockIdx.x * 256 + threadIdx.x) >> 6);
  const int lane = threadIdx.x & 63;
  if (gw >= Bn * NPOINT) return;
  const int b = gw >> 10;
  const float* px = xyz + b * Nn * 3;
  const float R2 = 0.04f;  // float(0.2*0.2 in double) == 0.04f

  float cx = new_xyz[gw * 3 + 0];
  float cy = new_xyz[gw * 3 + 1];
  float cz = new_xyz[gw * 3 + 2];
  float cs;
  {
#pragma clang fp contract(off)
    cs = (cx * cx + cy * cy) + cz * cz;
  }

  int* out = bidx + gw * NSAMPLE;
  int found = 0;
  int first = -1;

  for (int base = 0; base < Nn && found < NSAMPLE; base += 64) {
    int i = base + lane;
    float x = px[i * 3 + 0];
    float y = px[i * 3 + 1];
    float z = px[i * 3 + 2];
    float ps, sqr;
    // dot like a GEMM k-loop: fma accumulation, k ascending
    float dot = fmaf(cx, x, 0.0f);
    dot = fmaf(cy, y, dot);
    dot = fmaf(cz, z, dot);
    {
#pragma clang fp contract(off)
      ps = (x * x + y * y) + z * z;
      sqr = (cs - 2.0f * dot) + ps;
    }
    bool pass = !(sqr > R2);
    unsigned long long m = __ballot(pass);
    if (first < 0 && m) first = base + (__ffsll(m) - 1);
    int rank = (int)__popcll(m & ((1ULL << lane) - 1ULL));
    int pos = found + rank;
    if (pass && pos < NSAMPLE) out[pos] = i;
    found += (int)__popcll(m);
  }

  int cnt = found < NSAMPLE ? found : NSAMPLE;
  for (int k = cnt + lane; k < NSAMPLE; k += 64) out[k] = first;
}

// ---------------------------------------------------------------------------
// Kernel 3: gather + concat + 3x (linear+ReLU) + max over samples, fused.
// One wave (64 threads) per centroid. X (32x67) and H (32x64) staged in LDS
// (same-wave LDS ops are in-order -> no barriers needed). Each thread owns
// output column d=lane; weight columns from global (L1/L2-resident, all
// blocks read the same ~65KB). Layer 2 computes both output halves
// (dd=lane, dd=lane+64) in ONE pass so the Xw broadcast reads are shared.
// ---------------------------------------------------------------------------
__global__ __launch_bounds__(64) void group_mlp_kernel(
    const float* __restrict__ xyz, const float* __restrict__ points,
    const float* __restrict__ w0, const float* __restrict__ b0,
    const float* __restrict__ w1, const float* __restrict__ b1,
    const float* __restrict__ w2, const float* __restrict__ b2,
    const float* __restrict__ new_xyz, const int* __restrict__ bidx,
    float* __restrict__ out_pts) {
  const int lane = threadIdx.x & 63;
  const int g = blockIdx.x;  // centroid id in [0, B*NPOINT)
  const int b = g >> 10;

  __shared__ __align__(16) float Xw[NSAMPLE][68];  // 67 used; stride 68 keeps rows 16B-aligned
  __shared__ __align__(16) float Hw[NSAMPLE][64];

  const int* bi = bidx + g * NSAMPLE;
  const float c0 = new_xyz[g * 3 + 0];
  const float c1 = new_xyz[g * 3 + 1];
  const float c2 = new_xyz[g * 3 + 2];

  // ---- gather/concat: X[k][0:3] = xyz[idx]-cen, X[k][3:67] = points[idx][0:64]
  for (int k = 0; k < NSAMPLE; ++k) {
    int id = bi[k];
    float v;
    if (lane < 3) {
      v = xyz[(b * Nn + id) * 3 + lane] - (lane == 0 ? c0 : (lane == 1 ? c1 : c2));
    } else {
      v = points[(b * Nn + id) * Cn + (lane - 3)];
    }
    Xw[k][lane] = v;
    if (lane < 3) Xw[k][64 + lane] = points[(b * Nn + id) * Cn + 61 + lane];
  }

  float acc[NSAMPLE];

  // ---- layer 0: 67 -> 64, ReLU  (out column d = lane)
  {
    float bb = b0[lane];
#pragma unroll
    for (int k = 0; k < NSAMPLE; ++k) acc[k] = bb;
    for (int c4 = 0; c4 < 16; ++c4) {
      float wa = w0[(c4 * 4 + 0) * 64 + lane];
      float wb = w0[(c4 * 4 + 1) * 64 + lane];
      float wc = w0[(c4 * 4 + 2) * 64 + lane];
      float wd = w0[(c4 * 4 + 3) * 64 + lane];
#pragma unroll
      for (int k = 0; k < NSAMPLE; ++k) {
        float4 xv = *(const float4*)&Xw[k][c4 * 4];  // uniform addr -> broadcast
        acc[k] += xv.x * wa + xv.y * wb + xv.z * wc + xv.w * wd;
      }
    }
    float wt0 = w0[64 * 64 + lane];
    float wt1 = w0[65 * 64 + lane];
    float wt2 = w0[66 * 64 + lane];
#pragma unroll
    for (int k = 0; k < NSAMPLE; ++k)
      acc[k] += Xw[k][64] * wt0 + Xw[k][65] * wt1 + Xw[k][66] * wt2;
#pragma unroll
    for (int k = 0; k < NSAMPLE; ++k) Hw[k][lane] = fmaxf(acc[k], 0.0f);
  }

  // ---- layer 1: 64 -> 64, ReLU (reads Hw, writes back into Xw)
  {
    float bb = b1[lane];
#pragma unroll
    for (int k = 0; k < NSAMPLE; ++k) acc[k] = bb;
    for (int c4 = 0; c4 < 16; ++c4) {
      float wa = w1[(c4 * 4 + 0) * 64 + lane];
      float wb = w1[(c4 * 4 + 1) * 64 + lane];
      float wc = w1[(c4 * 4 + 2) * 64 + lane];
      float wd = w1[(c4 * 4 + 3) * 64 + lane];
#pragma unroll
      for (int k = 0; k < NSAMPLE; ++k) {
        float4 hv = *(const float4*)&Hw[k][c4 * 4];
        acc[k] += hv.x * wa + hv.y * wb + hv.z * wc + hv.w * wd;
      }
    }
#pragma unroll
    for (int k = 0; k < NSAMPLE; ++k) Xw[k][lane] = fmaxf(acc[k], 0.0f);
  }

  // ---- layer 2: 64 -> 128, ReLU + max over k; BOTH halves in one pass so
  // each Xw broadcast read feeds 8 FMAs instead of 4.
  {
    float accB[NSAMPLE];
    float bbA = b2[lane];
    float bbB = b2[lane + 64];
#pragma unroll
    for (int k = 0; k < NSAMPLE; ++k) { acc[k] = bbA; accB[k] = bbB; }
    for (int c4 = 0; c4 < 16; ++c4) {
      float wa = w2[(c4 * 4 + 0) * 128 + lane];
      float wb = w2[(c4 * 4 + 1) * 128 + lane];
      float wc = w2[(c4 * 4 + 2) * 128 + lane];
      float wd = w2[(c4 * 4 + 3) * 128 + lane];
      float we = w2[(c4 * 4 + 0) * 128 + lane + 64];
      float wf = w2[(c4 * 4 + 1) * 128 + lane + 64];
      float wg = w2[(c4 * 4 + 2) * 128 + lane + 64];
      float wh = w2[(c4 * 4 + 3) * 128 + lane + 64];
#pragma unroll
      for (int k = 0; k < NSAMPLE; ++k) {
        float4 xv = *(const float4*)&Xw[k][c4 * 4];
        acc[k]  += xv.x * wa + xv.y * wb + xv.z * wc + xv.w * wd;
        accB[k] += xv.x * we + xv.y * wf + xv.z * wg + xv.w * wh;
      }
    }
    // max_k relu(acc_k) == max(0, max_k acc_k)
    float mA = 0.0f, mB = 0.0f;
#pragma unroll
    for (int k = 0; k < NSAMPLE; ++k) {
      mA = fmaxf(mA, acc[k]);
      mB = fmaxf(mB, accB[k]);
    }
    float* outp = out_pts + g * 128;
    outp[lane] = mA;
    outp[lane + 64] = mB;
  }
}

// ---------------------------------------------------------------------------
extern "C" void kernel_launch(void* const* d_in, const int* in_sizes, int n_in,
                              void* d_out, int out_size, void* d_ws, size_t ws_size,
                              hipStream_t stream) {
  const float* xyz    = (const float*)d_in[0];
  const float* points = (const float*)d_in[1];
  const float* w0     = (const float*)d_in[2];
  const float* b0     = (const float*)d_in[3];
  const float* w1     = (const float*)d_in[4];
  const float* b1     = (const float*)d_in[5];
  const float* w2     = (const float*)d_in[6];
  const float* b2     = (const float*)d_in[7];

  float* new_xyz = (float*)d_out;                    // (B, NPOINT, 3)
  float* new_pts = (float*)d_out + Bn * NPOINT * 3;  // (B, NPOINT, 128)
  int*   bidx    = (int*)d_ws;                       // (B*NPOINT, NSAMPLE)

  fps_kernel<<<Bn, 256, 0, stream>>>(xyz, new_xyz);
  ballquery_kernel<<<(Bn * NPOINT) / 4, 256, 0, stream>>>(xyz, new_xyz, bidx);
  group_mlp_kernel<<<Bn * NPOINT, 64, 0, stream>>>(xyz, points, w0, b0, w1, b1,
                                                   w2, b2, new_xyz, bidx, new_pts);
}

// Round 6
// 1123.582 us; speedup vs baseline: 1.1089x; 1.0661x over previous
//
#include <hip/hip_runtime.h>
#include <cstdint>

#define Bn 16
#define Nn 4096
#define Cn 64
#define NPOINT 1024
#define NSAMPLE 32

#define FPS_T 512   // threads per FPS block (8 waves)
#define FPS_W (FPS_T / 64)
#define FPS_P (Nn / FPS_T)       // points per thread = 8
#define FPS_PAIRS (FPS_P / 2)    // f32x2 pairs per thread = 4

typedef float f32x2 __attribute__((ext_vector_type(2)));

// ---------------------------------------------------------------------------
// u64 argmax key: (dist_bits << 32) | ~index.
// dist >= 0 so its IEEE bits are monotone as u32; max key = max dist,
// ties -> max ~index = MIN index (matches jnp.argmax first-occurrence).
// ---------------------------------------------------------------------------
__device__ __forceinline__ unsigned long long fps_wave_max(unsigned long long k) {
  // Canonical GCN/CDNA wave64 prefix reduction via DPP; lane 63 ends with max.
#define FPS_STEP(CTRL)                                                          \
  {                                                                             \
    unsigned int lo = (unsigned int)k, hi = (unsigned int)(k >> 32);            \
    unsigned int tlo =                                                          \
        (unsigned int)__builtin_amdgcn_update_dpp((int)lo, (int)lo, CTRL, 0xF, 0xF, false); \
    unsigned int thi =                                                          \
        (unsigned int)__builtin_amdgcn_update_dpp((int)hi, (int)hi, CTRL, 0xF, 0xF, false); \
    unsigned long long t = ((unsigned long long)thi << 32) | tlo;               \
    if (t > k) k = t;                                                           \
  }
  FPS_STEP(0x111)  // row_shr:1
  FPS_STEP(0x112)  // row_shr:2
  FPS_STEP(0x114)  // row_shr:4
  FPS_STEP(0x118)  // row_shr:8  -> lane15 of each row16 has row max
  FPS_STEP(0x142)  // row_bcast:15 -> lane31 has max of lanes 0..31
  FPS_STEP(0x143)  // row_bcast:31 -> lane63 has max of lanes 0..63
#undef FPS_STEP
  return k;
}

// ---------------------------------------------------------------------------
// Kernel 1: farthest point sampling. One block (512 threads / 8 waves) per
// batch. 8 points/thread in packed f32x2 registers; float4 point mirror in
// LDS for the centroid broadcast. Centroid log in LDS, dumped once at the
// end. One barrier per iteration (double-buffered partials). Per-point
// numerics identical to the previously passing 256-thread version.
// ---------------------------------------------------------------------------
__global__ __launch_bounds__(FPS_T) void fps_kernel(const float* __restrict__ xyz,
                                                    float* __restrict__ new_xyz) {
  const int b = blockIdx.x;
  const int t = threadIdx.x;
  const float* px = xyz + b * Nn * 3;

  __shared__ __align__(16) float4 sp[Nn];               // 64 KiB point mirror
  __shared__ __align__(16) float sc[NPOINT * 3];        // 12 KiB centroid log
  __shared__ __align__(16) unsigned long long rk[2][FPS_W];

  f32x2 X2[FPS_PAIRS], Y2[FPS_PAIRS], Z2[FPS_PAIRS], D2[FPS_PAIRS];
#pragma unroll
  for (int p = 0; p < FPS_PAIRS; ++p) {
    int i0 = (2 * p) * FPS_T + t;
    int i1 = (2 * p + 1) * FPS_T + t;
    float x0 = px[i0 * 3 + 0], y0 = px[i0 * 3 + 1], z0 = px[i0 * 3 + 2];
    float x1 = px[i1 * 3 + 0], y1 = px[i1 * 3 + 1], z1 = px[i1 * 3 + 2];
    sp[i0] = make_float4(x0, y0, z0, 0.0f);
    sp[i1] = make_float4(x1, y1, z1, 0.0f);
    X2[p] = (f32x2){x0, x1};
    Y2[p] = (f32x2){y0, y1};
    Z2[p] = (f32x2){z0, z1};
    D2[p] = (f32x2){1e10f, 1e10f};
  }
  __syncthreads();

  int far = 0;

  for (int it = 0; it < NPOINT; ++it) {
    float4 c = sp[far];  // uniform address -> LDS broadcast
    if (t == 0) {        // LDS-only log; no global store inside the loop
      sc[it * 3 + 0] = c.x;
      sc[it * 3 + 1] = c.y;
      sc[it * 3 + 2] = c.z;
    }

    f32x2 cx2 = {c.x, c.x};
    f32x2 cy2 = {c.y, c.y};
    f32x2 cz2 = {c.z, c.z};

    float bd = -1.0f;
    int   bi = 0;
#pragma unroll
    for (int p = 0; p < FPS_PAIRS; ++p) {
#pragma clang fp contract(off)
      // mul+add (no fma), left-assoc: matches XLA's elementwise lowering.
      f32x2 dx = X2[p] - cx2;
      f32x2 dy = Y2[p] - cy2;
      f32x2 dz = Z2[p] - cz2;
      f32x2 d2 = (dx * dx + dy * dy) + dz * dz;
      f32x2 nd = __builtin_elementwise_min(D2[p], d2);
      D2[p] = nd;
      // ascending global index order; strict > keeps the lowest index
      float n0 = nd[0];
      if (n0 > bd) { bd = n0; bi = (2 * p) * FPS_T + t; }
      float n1 = nd[1];
      if (n1 > bd) { bd = n1; bi = (2 * p + 1) * FPS_T + t; }
    }

    unsigned long long k =
        ((unsigned long long)__float_as_uint(bd) << 32) |
        (unsigned int)(~(unsigned int)bi);
    k = fps_wave_max(k);  // lane 63 of each wave holds the wave max

    const int buf = it & 1;
    if ((t & 63) == 63) rk[buf][t >> 6] = k;
    __syncthreads();

    // all threads redundantly reduce the FPS_W partials -> same winner
    unsigned long long f0 = rk[buf][0];
#pragma unroll
    for (int w = 1; w < FPS_W; ++w) {
      unsigned long long fw = rk[buf][w];
      if (fw > f0) f0 = fw;
    }
    far = (int)(~(unsigned int)f0);  // recover index from ~idx in low bits
  }

  float* out = new_xyz + b * NPOINT * 3;
  for (int i = t; i < NPOINT * 3; i += FPS_T) out[i] = sc[i];
}

// ---------------------------------------------------------------------------
// Kernel 2: ball query (UNCHANGED).
// ---------------------------------------------------------------------------
__global__ __launch_bounds__(256) void ballquery_kernel(const float* __restrict__ xyz,
                                                        const float* __restrict__ new_xyz,
                                                        int* __restrict__ bidx) {
  const int gw = (int)((blockIdx.x * 256 + threadIdx.x) >> 6);
  const int lane = threadIdx.x & 63;
  if (gw >= Bn * NPOINT) return;
  const int b = gw >> 10;
  const float* px = xyz + b * Nn * 3;
  const float R2 = 0.04f;

  float cx = new_xyz[gw * 3 + 0];
  float cy = new_xyz[gw * 3 + 1];
  float cz = new_xyz[gw * 3 + 2];
  float cs;
  {
#pragma clang fp contract(off)
    cs = (cx * cx + cy * cy) + cz * cz;
  }

  int* out = bidx + gw * NSAMPLE;
  int found = 0;
  int first = -1;

  for (int base = 0; base < Nn && found < NSAMPLE; base += 64) {
    int i = base + lane;
    float x = px[i * 3 + 0];
    float y = px[i * 3 + 1];
    float z = px[i * 3 + 2];
    float ps, sqr;
    float dot = fmaf(cx, x, 0.0f);
    dot = fmaf(cy, y, dot);
    dot = fmaf(cz, z, dot);
    {
#pragma clang fp contract(off)
      ps = (x * x + y * y) + z * z;
      sqr = (cs - 2.0f * dot) + ps;
    }
    bool pass = !(sqr > R2);
    unsigned long long m = __ballot(pass);
    if (first < 0 && m) first = base + (__ffsll(m) - 1);
    int rank = (int)__popcll(m & ((1ULL << lane) - 1ULL));
    int pos = found + rank;
    if (pass && pos < NSAMPLE) out[pos] = i;
    found += (int)__popcll(m);
  }

  int cnt = found < NSAMPLE ? found : NSAMPLE;
  for (int k = cnt + lane; k < NSAMPLE; k += 64) out[k] = first;
}

// ---------------------------------------------------------------------------
// Kernel 3: register-resident per-sample MLP (UNCHANGED from R4; unbenched).
// One wave = TWO groups: lane -> (h = lane>>5, k = lane&31). acc[d] in
// registers; W rows are wave-uniform -> SGPR broadcast via s_load. LDS only
// holds the per-lane activations column-major (conflict-free both ways).
// ---------------------------------------------------------------------------
__global__ __launch_bounds__(64) void group_mlp_kernel(
    const float* __restrict__ xyz, const float* __restrict__ points,
    const float* __restrict__ w0, const float* __restrict__ b0,
    const float* __restrict__ w1, const float* __restrict__ b1,
    const float* __restrict__ w2, const float* __restrict__ b2,
    const float* __restrict__ new_xyz, const int* __restrict__ bidx,
    float* __restrict__ out_pts) {
  const int lane = threadIdx.x;      // 0..63
  const int k = lane & 31;           // sample within group
  const int g = blockIdx.x * 2 + (lane >> 5);  // group id
  const int b = g >> 10;

  __shared__ float Xs[68][64];  // [feature][lane], column-major per lane

  const int id = bidx[g * NSAMPLE + k];

  // ---- gather: Xs[0..2] = xyz[id]-centroid, Xs[3..66] = points[id][0..63]
  {
    const float* p3 = xyz + (b * Nn + id) * 3;
    Xs[0][lane] = p3[0] - new_xyz[g * 3 + 0];
    Xs[1][lane] = p3[1] - new_xyz[g * 3 + 1];
    Xs[2][lane] = p3[2] - new_xyz[g * 3 + 2];
  }
  {
    const float* prow = points + (size_t)(b * Nn + id) * Cn;
#pragma unroll
    for (int q = 0; q < 16; ++q) {
      float4 v = *(const float4*)(prow + q * 4);
      Xs[3 + q * 4 + 0][lane] = v.x;
      Xs[3 + q * 4 + 1][lane] = v.y;
      Xs[3 + q * 4 + 2][lane] = v.z;
      Xs[3 + q * 4 + 3][lane] = v.w;
    }
  }
  // single wave per block: same-wave LDS ops are in-order, no barrier needed

  float A[64];

  // ---- layer 0: 67 -> 64, +bias, ReLU
#pragma unroll
  for (int d = 0; d < 64; ++d) A[d] = 0.0f;
  for (int c = 0; c < 67; ++c) {
    float xc = Xs[c][lane];
    const float* wr = w0 + c * 64;  // wave-uniform row -> s_load
#pragma unroll
    for (int d = 0; d < 64; ++d) A[d] = fmaf(xc, wr[d], A[d]);
  }
#pragma unroll
  for (int d = 0; d < 64; ++d) A[d] = fmaxf(A[d] + b0[d], 0.0f);
#pragma unroll
  for (int d = 0; d < 64; ++d) Xs[d][lane] = A[d];

  // ---- layer 1: 64 -> 64, +bias, ReLU
#pragma unroll
  for (int d = 0; d < 64; ++d) A[d] = 0.0f;
  for (int c = 0; c < 64; ++c) {
    float xc = Xs[c][lane];
    const float* wr = w1 + c * 64;
#pragma unroll
    for (int d = 0; d < 64; ++d) A[d] = fmaf(xc, wr[d], A[d]);
  }
#pragma unroll
  for (int d = 0; d < 64; ++d) A[d] = fmaxf(A[d] + b1[d], 0.0f);
#pragma unroll
  for (int d = 0; d < 64; ++d) Xs[d][lane] = A[d];

  // ---- layer 2: 64 -> 128 in two passes of 64, +bias, ReLU, maxpool over k
  float* outp = out_pts + (size_t)g * 128;
#pragma unroll 1
  for (int pass = 0; pass < 2; ++pass) {
#pragma unroll
    for (int d = 0; d < 64; ++d) A[d] = 0.0f;
    for (int c = 0; c < 64; ++c) {
      float xc = Xs[c][lane];
      const float* wr = w2 + c * 128 + pass * 64;
#pragma unroll
      for (int d = 0; d < 64; ++d) A[d] = fmaf(xc, wr[d], A[d]);
    }
#pragma unroll
    for (int d = 0; d < 64; ++d) A[d] = fmaxf(A[d] + b2[pass * 64 + d], 0.0f);

    // max over the 32 samples: xor butterfly stays within each 32-lane half
#pragma unroll 1
    for (int off = 1; off < 32; off <<= 1) {
#pragma unroll
      for (int d = 0; d < 64; ++d) A[d] = fmaxf(A[d], __shfl_xor(A[d], off, 64));
    }
    if (k == 0) {
#pragma unroll
      for (int q = 0; q < 16; ++q)
        *(float4*)(outp + pass * 64 + q * 4) =
            make_float4(A[q * 4 + 0], A[q * 4 + 1], A[q * 4 + 2], A[q * 4 + 3]);
    }
  }
}

// ---------------------------------------------------------------------------
extern "C" void kernel_launch(void* const* d_in, const int* in_sizes, int n_in,
                              void* d_out, int out_size, void* d_ws, size_t ws_size,
                              hipStream_t stream) {
  const float* xyz    = (const float*)d_in[0];
  const float* points = (const float*)d_in[1];
  const float* w0     = (const float*)d_in[2];
  const float* b0     = (const float*)d_in[3];
  const float* w1     = (const float*)d_in[4];
  const float* b1     = (const float*)d_in[5];
  const float* w2     = (const float*)d_in[6];
  const float* b2     = (const float*)d_in[7];

  float* new_xyz = (float*)d_out;                    // (B, NPOINT, 3)
  float* new_pts = (float*)d_out + Bn * NPOINT * 3;  // (B, NPOINT, 128)
  int*   bidx    = (int*)d_ws;                       // (B*NPOINT, NSAMPLE)

  fps_kernel<<<Bn, FPS_T, 0, stream>>>(xyz, new_xyz);
  ballquery_kernel<<<(Bn * NPOINT) / 4, 256, 0, stream>>>(xyz, new_xyz, bidx);
  group_mlp_kernel<<<(Bn * NPOINT) / 2, 64, 0, stream>>>(xyz, points, w0, b0,
                                                         w1, b1, w2, b2,
                                                         new_xyz, bidx, new_pts);
}

// Round 13
// 1035.943 us; speedup vs baseline: 1.2028x; 1.0846x over previous
//
#include <hip/hip_runtime.h>
#include <cstdint>

#define Bn 16
#define Nn 4096
#define Cn 64
#define NPOINT 1024
#define NSAMPLE 32

typedef float f32x2 __attribute__((ext_vector_type(2)));

// ---------------------------------------------------------------------------
// u64 argmax key: (dist_bits << 32) | ~index.
// dist >= 0 so its IEEE bits are monotone as u32; max key = max dist,
// ties -> max ~index = MIN index (matches jnp.argmax first-occurrence).
// ---------------------------------------------------------------------------
__device__ __forceinline__ unsigned long long fps_wave_max(unsigned long long k) {
  // Canonical GCN/CDNA wave64 prefix reduction via DPP; lane 63 ends with max.
#define FPS_STEP(CTRL)                                                          \
  {                                                                             \
    unsigned int lo = (unsigned int)k, hi = (unsigned int)(k >> 32);            \
    unsigned int tlo =                                                          \
        (unsigned int)__builtin_amdgcn_update_dpp((int)lo, (int)lo, CTRL, 0xF, 0xF, false); \
    unsigned int thi =                                                          \
        (unsigned int)__builtin_amdgcn_update_dpp((int)hi, (int)hi, CTRL, 0xF, 0xF, false); \
    unsigned long long t = ((unsigned long long)thi << 32) | tlo;               \
    if (t > k) k = t;                                                           \
  }
  FPS_STEP(0x111)  // row_shr:1
  FPS_STEP(0x112)  // row_shr:2
  FPS_STEP(0x114)  // row_shr:4
  FPS_STEP(0x118)  // row_shr:8  -> lane15 of each row16 has row max
  FPS_STEP(0x142)  // row_bcast:15 -> lane31 has max of lanes 0..31
  FPS_STEP(0x143)  // row_bcast:31 -> lane63 has max of lanes 0..63
#undef FPS_STEP
  return k;
}

// ---------------------------------------------------------------------------
// Kernel 1: farthest point sampling — 256-thread version (measured 595us;
// the 512-thread variant regressed to 682us: waves sharing a SIMD issue port
// don't shorten the serial distance loop). One block (4 waves = 1 wave/SIMD)
// per batch; 16 points/thread in f32x2 pairs; centroid log in LDS, dumped
// once at the end; one barrier per iteration (double-buffered partials).
// ---------------------------------------------------------------------------
__global__ __launch_bounds__(256) void fps_kernel(const float* __restrict__ xyz,
                                                  float* __restrict__ new_xyz) {
  const int b = blockIdx.x;
  const int t = threadIdx.x;
  const float* px = xyz + b * Nn * 3;

  __shared__ __align__(16) float4 sp[Nn];               // 64 KiB point mirror
  __shared__ __align__(16) float sc[NPOINT * 3];        // 12 KiB centroid log
  __shared__ __align__(16) unsigned long long rk[2][4];

  f32x2 X2[8], Y2[8], Z2[8], D2[8];
#pragma unroll
  for (int p = 0; p < 8; ++p) {
    int i0 = (2 * p) * 256 + t;
    int i1 = (2 * p + 1) * 256 + t;
    float x0 = px[i0 * 3 + 0], y0 = px[i0 * 3 + 1], z0 = px[i0 * 3 + 2];
    float x1 = px[i1 * 3 + 0], y1 = px[i1 * 3 + 1], z1 = px[i1 * 3 + 2];
    sp[i0] = make_float4(x0, y0, z0, 0.0f);
    sp[i1] = make_float4(x1, y1, z1, 0.0f);
    X2[p] = (f32x2){x0, x1};
    Y2[p] = (f32x2){y0, y1};
    Z2[p] = (f32x2){z0, z1};
    D2[p] = (f32x2){1e10f, 1e10f};
  }
  __syncthreads();

  int far = 0;

  for (int it = 0; it < NPOINT; ++it) {
    float4 c = sp[far];  // uniform address -> LDS broadcast
    if (t == 0) {        // LDS-only log; no global store inside the loop
      sc[it * 3 + 0] = c.x;
      sc[it * 3 + 1] = c.y;
      sc[it * 3 + 2] = c.z;
    }

    f32x2 cx2 = {c.x, c.x};
    f32x2 cy2 = {c.y, c.y};
    f32x2 cz2 = {c.z, c.z};

    float bd = -1.0f;
    int   bi = 0;
#pragma unroll
    for (int p = 0; p < 8; ++p) {
#pragma clang fp contract(off)
      f32x2 dx = X2[p] - cx2;
      f32x2 dy = Y2[p] - cy2;
      f32x2 dz = Z2[p] - cz2;
      f32x2 d2 = (dx * dx + dy * dy) + dz * dz;
      f32x2 nd = __builtin_elementwise_min(D2[p], d2);
      D2[p] = nd;
      float n0 = nd[0];
      if (n0 > bd) { bd = n0; bi = (2 * p) * 256 + t; }
      float n1 = nd[1];
      if (n1 > bd) { bd = n1; bi = (2 * p + 1) * 256 + t; }
    }

    unsigned long long k =
        ((unsigned long long)__float_as_uint(bd) << 32) |
        (unsigned int)(~(unsigned int)bi);
    k = fps_wave_max(k);  // lane 63 of each wave holds the wave max

    const int buf = it & 1;
    if ((t & 63) == 63) rk[buf][t >> 6] = k;
    __syncthreads();

    unsigned long long f0 = rk[buf][0];
    unsigned long long f1 = rk[buf][1];
    unsigned long long f2 = rk[buf][2];
    unsigned long long f3 = rk[buf][3];
    if (f1 > f0) f0 = f1;
    if (f2 > f0) f0 = f2;
    if (f3 > f0) f0 = f3;
    far = (int)(~(unsigned int)f0);
  }

  float* out = new_xyz + b * NPOINT * 3;
  for (int i = t; i < NPOINT * 3; i += 256) out[i] = sc[i];
}

// ---------------------------------------------------------------------------
// Kernel 2: ball query (UNCHANGED).
// ---------------------------------------------------------------------------
__global__ __launch_bounds__(256) void ballquery_kernel(const float* __restrict__ xyz,
                                                        const float* __restrict__ new_xyz,
                                                        int* __restrict__ bidx) {
  const int gw = (int)((blockIdx.x * 256 + threadIdx.x) >> 6);
  const int lane = threadIdx.x & 63;
  if (gw >= Bn * NPOINT) return;
  const int b = gw >> 10;
  const float* px = xyz + b * Nn * 3;
  const float R2 = 0.04f;

  float cx = new_xyz[gw * 3 + 0];
  float cy = new_xyz[gw * 3 + 1];
  float cz = new_xyz[gw * 3 + 2];
  float cs;
  {
#pragma clang fp contract(off)
    cs = (cx * cx + cy * cy) + cz * cz;
  }

  int* out = bidx + gw * NSAMPLE;
  int found = 0;
  int first = -1;

  for (int base = 0; base < Nn && found < NSAMPLE; base += 64) {
    int i = base + lane;
    float x = px[i * 3 + 0];
    float y = px[i * 3 + 1];
    float z = px[i * 3 + 2];
    float ps, sqr;
    float dot = fmaf(cx, x, 0.0f);
    dot = fmaf(cy, y, dot);
    dot = fmaf(cz, z, dot);
    {
#pragma clang fp contract(off)
      ps = (x * x + y * y) + z * z;
      sqr = (cs - 2.0f * dot) + ps;
    }
    bool pass = !(sqr > R2);
    unsigned long long m = __ballot(pass);
    if (first < 0 && m) first = base + (__ffsll(m) - 1);
    int rank = (int)__popcll(m & ((1ULL << lane) - 1ULL));
    int pos = found + rank;
    if (pass && pos < NSAMPLE) out[pos] = i;
    found += (int)__popcll(m);
  }

  int cnt = found < NSAMPLE ? found : NSAMPLE;
  for (int k = cnt + lane; k < NSAMPLE; k += 64) out[k] = first;
}

// ---------------------------------------------------------------------------
// Kernel 3: register-resident per-sample MLP, v3 + unroll-2 ILP hedge.
// Weight rows via per-lane GLOBAL vector loads (same-address across the wave
// -> one L1 transaction, broadcast). #pragma unroll 2 on the c-loops forces
// >=2 weight rows in flight under the fma chains (vmcnt pipelining).
// Accumulation order per A[d] (c ascending fmaf chain) unchanged -> bit-exact
// with the R6 run (absmax 0.0).
// ---------------------------------------------------------------------------
__global__ __launch_bounds__(64) void group_mlp_kernel(
    const float* __restrict__ xyz, const float* __restrict__ points,
    const float* __restrict__ w0, const float* __restrict__ b0,
    const float* __restrict__ w1, const float* __restrict__ b1,
    const float* __restrict__ w2, const float* __restrict__ b2,
    const float* __restrict__ new_xyz, const int* __restrict__ bidx,
    float* __restrict__ out_pts) {
  const int lane = threadIdx.x;      // 0..63
  const int k = lane & 31;           // sample within group
  const int g = blockIdx.x * 2 + (lane >> 5);  // group id
  const int b = g >> 10;

  __shared__ float Xs[68][64];  // [feature][lane], column-major per lane

  const int id = bidx[g * NSAMPLE + k];

  // ---- gather: Xs[0..2] = xyz[id]-centroid, Xs[3..66] = points[id][0..63]
  {
    const float* p3 = xyz + (b * Nn + id) * 3;
    Xs[0][lane] = p3[0] - new_xyz[g * 3 + 0];
    Xs[1][lane] = p3[1] - new_xyz[g * 3 + 1];
    Xs[2][lane] = p3[2] - new_xyz[g * 3 + 2];
  }
  {
    const float* prow = points + (size_t)(b * Nn + id) * Cn;
#pragma unroll
    for (int q = 0; q < 16; ++q) {
      float4 v = *(const float4*)(prow + q * 4);
      Xs[3 + q * 4 + 0][lane] = v.x;
      Xs[3 + q * 4 + 1][lane] = v.y;
      Xs[3 + q * 4 + 2][lane] = v.z;
      Xs[3 + q * 4 + 3][lane] = v.w;
    }
  }
  // single wave per block: same-wave LDS ops are in-order, no barrier needed

  float A[64];

  // FMA64: A[d] += xc * wrow[d], weight row loaded as 16 float4 (uniform
  // address across lanes -> L1 broadcast; deep vmcnt pipelining across c).
#define FMA64(WPTR)                                                   \
  {                                                                   \
    _Pragma("unroll")                                                 \
    for (int q = 0; q < 16; ++q) {                                    \
      float4 wv = *(const float4*)((WPTR) + q * 4);                   \
      A[q * 4 + 0] = fmaf(xc, wv.x, A[q * 4 + 0]);                    \
      A[q * 4 + 1] = fmaf(xc, wv.y, A[q * 4 + 1]);                    \
      A[q * 4 + 2] = fmaf(xc, wv.z, A[q * 4 + 2]);                    \
      A[q * 4 + 3] = fmaf(xc, wv.w, A[q * 4 + 3]);                    \
    }                                                                 \
  }

#define BIAS_RELU(BPTR)                                               \
  {                                                                   \
    _Pragma("unroll")                                                 \
    for (int q = 0; q < 16; ++q) {                                    \
      float4 bv = *(const float4*)((BPTR) + q * 4);                   \
      A[q * 4 + 0] = fmaxf(A[q * 4 + 0] + bv.x, 0.0f);                \
      A[q * 4 + 1] = fmaxf(A[q * 4 + 1] + bv.y, 0.0f);                \
      A[q * 4 + 2] = fmaxf(A[q * 4 + 2] + bv.z, 0.0f);                \
      A[q * 4 + 3] = fmaxf(A[q * 4 + 3] + bv.w, 0.0f);                \
    }                                                                 \
  }

  // ---- layer 0: 67 -> 64, +bias, ReLU
#pragma unroll
  for (int d = 0; d < 64; ++d) A[d] = 0.0f;
#pragma unroll 2
  for (int c = 0; c < 67; ++c) {
    float xc = Xs[c][lane];
    FMA64(w0 + c * 64);
  }
  BIAS_RELU(b0);
#pragma unroll
  for (int d = 0; d < 64; ++d) Xs[d][lane] = A[d];

  // ---- layer 1: 64 -> 64, +bias, ReLU
#pragma unroll
  for (int d = 0; d < 64; ++d) A[d] = 0.0f;
#pragma unroll 2
  for (int c = 0; c < 64; ++c) {
    float xc = Xs[c][lane];
    FMA64(w1 + c * 64);
  }
  BIAS_RELU(b1);
#pragma unroll
  for (int d = 0; d < 64; ++d) Xs[d][lane] = A[d];

  // ---- layer 2: 64 -> 128 in two passes of 64, +bias, ReLU, maxpool over k
  float* outp = out_pts + (size_t)g * 128;
#pragma unroll 1
  for (int pass = 0; pass < 2; ++pass) {
#pragma unroll
    for (int d = 0; d < 64; ++d) A[d] = 0.0f;
#pragma unroll 2
    for (int c = 0; c < 64; ++c) {
      float xc = Xs[c][lane];
      FMA64(w2 + c * 128 + pass * 64);
    }
    BIAS_RELU(b2 + pass * 64);

    // max over the 32 samples: xor butterfly stays within each 32-lane half
#pragma unroll 1
    for (int off = 1; off < 32; off <<= 1) {
#pragma unroll
      for (int d = 0; d < 64; ++d) A[d] = fmaxf(A[d], __shfl_xor(A[d], off, 64));
    }
    if (k == 0) {
#pragma unroll
      for (int q = 0; q < 16; ++q)
        *(float4*)(outp + pass * 64 + q * 4) =
            make_float4(A[q * 4 + 0], A[q * 4 + 1], A[q * 4 + 2], A[q * 4 + 3]);
    }
  }
#undef FMA64
#undef BIAS_RELU
}

// ---------------------------------------------------------------------------
extern "C" void kernel_launch(void* const* d_in, const int* in_sizes, int n_in,
                              void* d_out, int out_size, void* d_ws, size_t ws_size,
                              hipStream_t stream) {
  const float* xyz    = (const float*)d_in[0];
  const float* points = (const float*)d_in[1];
  const float* w0     = (const float*)d_in[2];
  const float* b0     = (const float*)d_in[3];
  const float* w1     = (const float*)d_in[4];
  const float* b1     = (const float*)d_in[5];
  const float* w2     = (const float*)d_in[6];
  const float* b2     = (const float*)d_in[7];

  float* new_xyz = (float*)d_out;                    // (B, NPOINT, 3)
  float* new_pts = (float*)d_out + Bn * NPOINT * 3;  // (B, NPOINT, 128)
  int*   bidx    = (int*)d_ws;                       // (B*NPOINT, NSAMPLE)

  fps_kernel<<<Bn, 256, 0, stream>>>(xyz, new_xyz);
  ballquery_kernel<<<(Bn * NPOINT) / 4, 256, 0, stream>>>(xyz, new_xyz, bidx);
  group_mlp_kernel<<<(Bn * NPOINT) / 2, 64, 0, stream>>>(xyz, points, w0, b0,
                                                         w1, b1, w2, b2,
                                                         new_xyz, bidx, new_pts);
}